// Round 8
// baseline (245.897 us; speedup 1.0000x reference)
//
#include <hip/hip_runtime.h>

// LightCoordAtt: x (N,C,H,W) f32 in, f32 out. N=16, C=256, H=W=80, mip=8, L=160.
//
// R8 = R7 resubmitted verbatim (R7 hit "MI355X container failed twice" -
// infra failure, no signal). Single variable vs R6: transposed pooled_t +
// latency-flat mid. Apply byte-identical to R4/R6.
//
// Journal: R1: cross-XCD atomicAdd fusion -> +62 us (NEVER: 84 MB writeback).
//          R3: NT stores -> -2 us (noise; kept).  R4: 4-plane apply -> -2.4.
//          R5: register-resident-x coop fusion -> +133 us (NEVER: VGPR payload
//              forces 2 waves/SIMD; whole kernel latency-bound).
//          R6: partial-sums pool -> -1.1 (noise; kept). Pool is NOT the sink.
//          Algebra (R5 calibration): F ~ 124 us fills; apply ~ 45 (near mixed
//          R/W HBM floor); pool ~ 20-25; mid + gaps ~ 20-25 <- this target.
#define N_   16
#define C_   256
#define H_   80
#define W_   80
#define MIP_ 8
#define L_   160

typedef float f32x4 __attribute__((ext_vector_type(4)));

// ---------------------------------------------------------------------------
// Kernel 1: per-(n,c) plane H-mean and W-mean, partial-sums form (R6),
// output TRANSPOSED: pooled_t[n][l][c] so mid reads c-contiguous rows.
// 160 scattered scalar stores per block (stride 1 KB); L2 write-combines
// across the 256 same-n blocks.
// ---------------------------------------------------------------------------
__global__ __launch_bounds__(320) void pool_kernel(const float* __restrict__ x,
                                                   float* __restrict__ pooled_t) {
    __shared__ float lds_row[H_][21];      // stride 21: gcd(21,32)=1 -> conflict-free
    __shared__ f32x4 lds_col[16][20];      // [rowgroup][colblock]
    const int b  = blockIdx.x;             // n*C_ + c
    const int n  = b >> 8;
    const int c  = b & 255;
    const int t  = threadIdx.x;            // 0..319
    const int c4 = t % 20;                 // column block (4 cols)
    const int rg = t / 20;                 // row group 0..15

    const f32x4* xv = reinterpret_cast<const f32x4*>(x + (size_t)b * (H_ * W_));
    f32x4 colacc = {0.f, 0.f, 0.f, 0.f};
    #pragma unroll
    for (int k = 0; k < 5; ++k) {
        f32x4 q = xv[t + 320 * k];         // row = rg+16k, cols 4*c4..4*c4+3
        colacc += q;
        lds_row[rg + 16 * k][c4] = q.x + q.y + q.z + q.w;
    }
    lds_col[rg][c4] = colacc;
    __syncthreads();

    float* outb = pooled_t + (size_t)n * (L_ * C_) + c;   // column c of n's [L][C] slab
    if (t < H_) {                          // waves 0-1: row means -> x_h (l = t)
        float s = 0.f;
        #pragma unroll
        for (int j = 0; j < 20; ++j) s += lds_row[t][j];
        outb[t * C_] = s * (1.0f / (float)W_);
    } else if (t >= 128 && t < 128 + 20) { // wave 2: col means -> x_w (l = 80+4j..)
        const int j = t - 128;
        f32x4 s = lds_col[0][j];
        #pragma unroll
        for (int r = 1; r < 16; ++r) s += lds_col[r][j];
        s *= (1.0f / (float)H_);
        outb[(H_ + 4 * j    ) * C_] = s.x;
        outb[(H_ + 4 * j + 1) * C_] = s.y;
        outb[(H_ + 4 * j + 2) * C_] = s.z;
        outb[(H_ + 4 * j + 3) * C_] = s.w;
    }
}

// ---------------------------------------------------------------------------
// Kernel 2: y[n,l,m] = swish( BN( sum_c w_fc[m,c] * pooled_t[n,l,c] ) )
// One block per n; thread t = l. Row read is c-contiguous f32x4 (64 loads);
// w_fc indices are wave-uniform after unroll -> scalar (s_load) broadcasts,
// K$-resident (8 KB). No shuffles, no barriers, no LDS.
// ---------------------------------------------------------------------------
__global__ __launch_bounds__(192) void mid_kernel(const float* __restrict__ pooled_t,
                                                  const float* __restrict__ w_fc,
                                                  const float* __restrict__ g,
                                                  const float* __restrict__ be,
                                                  const float* __restrict__ mu,
                                                  const float* __restrict__ va,
                                                  float* __restrict__ y_out) {
    const int n = blockIdx.x;             // 0..15
    const int t = threadIdx.x;            // 0..191, active t < 160
    if (t >= L_) return;

    const f32x4* row = reinterpret_cast<const f32x4*>(pooled_t + ((size_t)n * L_ + t) * C_);
    const f32x4* wv  = reinterpret_cast<const f32x4*>(w_fc);   // [8][64] f32x4 view

    float acc[MIP_] = {0.f, 0.f, 0.f, 0.f, 0.f, 0.f, 0.f, 0.f};
    #pragma unroll 8
    for (int c4 = 0; c4 < 64; ++c4) {
        const f32x4 p = row[c4];
        #pragma unroll
        for (int m = 0; m < MIP_; ++m) {
            const f32x4 w4 = wv[m * 64 + c4];      // uniform -> scalarized
            acc[m] += p.x * w4.x + p.y * w4.y + p.z * w4.z + p.w * w4.w;
        }
    }

    f32x4 o0, o1;
    #pragma unroll
    for (int m = 0; m < MIP_; ++m) {
        const float inv = g[m] * rsqrtf(va[m] + 1e-5f);        // uniform
        float s = acc[m] * inv + (be[m] - mu[m] * inv);
        s = s / (1.0f + expf(-s));                              // swish
        if (m < 4) { (m == 0) ? (o0.x = s) : (m == 1) ? (o0.y = s) : (m == 2) ? (o0.z = s) : (o0.w = s); }
        else       { (m == 4) ? (o1.x = s) : (m == 5) ? (o1.y = s) : (m == 6) ? (o1.z = s) : (o1.w = s); }
    }
    f32x4* yp = reinterpret_cast<f32x4*>(y_out + ((size_t)n * L_ + t) * MIP_);
    yp[0] = o0;                            // 32B/thread, coalesced
    yp[1] = o1;
}

// ---------------------------------------------------------------------------
// Kernel 3: 4 planes per block (byte-identical to R4/R6).
// ---------------------------------------------------------------------------
__global__ __launch_bounds__(256) void apply_kernel(const float* __restrict__ x,
                                                    const float* __restrict__ y,
                                                    const float* __restrict__ w_h,
                                                    const float* __restrict__ w_w,
                                                    float* __restrict__ out) {
    __shared__ float lah[4][H_];
    __shared__ float law[4][W_];
    const int b  = blockIdx.x;            // 0..1023
    const int n  = b >> 6;                // b / 64
    const int c0 = (b & 63) << 2;         // 4 * (b % 64)
    const int t  = threadIdx.x;

    #pragma unroll
    for (int pass = 0; pass < 3; ++pass) {
        int idx = t + pass * 256;
        if (idx < 4 * L_) {
            int ch = idx / L_;
            int l  = idx - ch * L_;
            int c  = c0 + ch;
            const float4* yp = reinterpret_cast<const float4*>(y + ((size_t)n * L_ + l) * MIP_);
            const float4* wp = reinterpret_cast<const float4*>(((l < H_) ? w_h : w_w) + c * MIP_);
            float4 y0 = yp[0], y1 = yp[1];
            float4 w0 = wp[0], w1 = wp[1];
            float s = y0.x * w0.x + y0.y * w0.y + y0.z * w0.z + y0.w * w0.w
                    + y1.x * w1.x + y1.y * w1.y + y1.z * w1.z + y1.w * w1.w;
            float gate = 1.0f / (1.0f + expf(-s));
            if (l < H_) lah[ch][l] = gate; else law[ch][l - H_] = gate;
        }
    }
    __syncthreads();

    const float4* xv = reinterpret_cast<const float4*>(x + ((size_t)n * C_ + c0) * (H_ * W_));
    f32x4*        ov = reinterpret_cast<f32x4*>(out + ((size_t)n * C_ + c0) * (H_ * W_));
    #pragma unroll
    for (int it = 0; it < 25; ++it) {             // 6400 = 25 * 256 exactly
        int v     = t + it * 256;
        int plane = v / 1600;
        int vv    = v - plane * 1600;
        int row   = vv / 20;
        int col0  = (vv - row * 20) * 4;
        float4 q  = xv[v];
        const float ah = lah[plane][row];
        const float* lw = &law[plane][col0];
        f32x4 o;
        o.x = q.x * ah * lw[0];
        o.y = q.y * ah * lw[1];
        o.z = q.z * ah * lw[2];
        o.w = q.w * ah * lw[3];
        __builtin_nontemporal_store(o, &ov[v]);   // out is write-once
    }
}

extern "C" void kernel_launch(void* const* d_in, const int* in_sizes, int n_in,
                              void* d_out, int out_size, void* d_ws, size_t ws_size,
                              hipStream_t stream) {
    const float* x    = (const float*)d_in[0];
    const float* w_fc = (const float*)d_in[1];
    const float* g    = (const float*)d_in[2];
    const float* be   = (const float*)d_in[3];
    const float* mu   = (const float*)d_in[4];
    const float* va   = (const float*)d_in[5];
    const float* w_h  = (const float*)d_in[6];
    const float* w_w  = (const float*)d_in[7];
    float* out = (float*)d_out;

    float* pooled_t = (float*)d_ws;                          // N*L*C floats = 2.62 MB
    float* y        = pooled_t + (size_t)N_ * L_ * C_;       // N*L*MIP floats = 80 KB

    pool_kernel <<<N_ * C_,     320, 0, stream>>>(x, pooled_t);
    mid_kernel  <<<N_,          192, 0, stream>>>(pooled_t, w_fc, g, be, mu, va, y);
    apply_kernel<<<N_ * C_ / 4, 256, 0, stream>>>(x, y, w_h, w_w, out);
}